// Round 1
// baseline (353.921 us; speedup 1.0000x reference)
//
#include <hip/hip_runtime.h>

// Problem: B=8, C=256, H=W=160. n = B*C = 2048 planes.
// Per plane: l[h]=x[h,:]·fcw_w ; alpha=softmax_h(l) ; row[w]=sum_h alpha[h]x[h,w]
//            beta=softmax_w(row*sum(fch_w)) ; s=sum_w beta[w]row[w] ; out[:,:]=s
// Biases are softmax-shift-invariant -> ignored.
//
// One block per plane. 320 threads = (q in [0,40), v in [0,8)).
// Thread owns float4 column block w in [4q,4q+4), rows h in [20v, 20v+20):
// 20 float4 in registers -> x read from HBM exactly once, fully coalesced.

#define HH 160
#define WW 160
#define NPLANE (HH * WW)
#define BLOCK 320
#define RPT 20   // rows per v-group
#define QN 40    // float4 columns per row
#define PSTR 41  // pad 41: bank = (9h+q)%32 -> conflict-free gather by h

__global__ void __launch_bounds__(BLOCK) sa1_kernel(
    const float* __restrict__ x,
    const float* __restrict__ fcw_w,
    const float* __restrict__ fch_w,
    float* __restrict__ out)
{
    const int n = blockIdx.x;
    const int t = threadIdx.x;
    const int q = t % QN;
    const int v = t / QN;

    __shared__ float pbuf[HH * PSTR];  // logit partials, later row partials [8][160]
    __shared__ float larr[HH];         // logits, later row[]
    __shared__ float sc[4];            // m, Z, S(=sum fch_w), s

    const float* xp = x + (size_t)n * NPLANE;
    float*       op = out + (size_t)n * NPLANE;

    const float4 ww = *(const float4*)(fcw_w + 4 * q);

    // ---- load my 20 float4 (coalesced: each wave covers contiguous runs) ----
    float4 xr[RPT];
#pragma unroll
    for (int r = 0; r < RPT; ++r)
        xr[r] = *(const float4*)(xp + (size_t)(v * RPT + r) * WW + 4 * q);

    // ---- logit partials: p(h,q) = x4 . ww4 ----
#pragma unroll
    for (int r = 0; r < RPT; ++r) {
        float p = xr[r].x * ww.x + xr[r].y * ww.y + xr[r].z * ww.z + xr[r].w * ww.w;
        pbuf[(v * RPT + r) * PSTR + q] = p;
    }
    __syncthreads();

    // ---- l[h] = sum_q p(h,q)  (threads 0..159, banks (9t+q)%32: 2-way, free) ----
    if (t < HH) {
        const float* pr = pbuf + t * PSTR;
        float s0 = 0.f, s1 = 0.f, s2 = 0.f, s3 = 0.f;
#pragma unroll
        for (int qq = 0; qq < QN; qq += 4) {
            s0 += pr[qq]; s1 += pr[qq + 1]; s2 += pr[qq + 2]; s3 += pr[qq + 3];
        }
        larr[t] = (s0 + s1) + (s2 + s3);
    }
    __syncthreads();

    // ---- wave0: softmax stats m, Z over l[0..159]; wave1: S = sum(fch_w) ----
    if (t < 32) {
        float lv[5];
#pragma unroll
        for (int j = 0; j < 5; ++j) lv[j] = larr[t + 32 * j];
        float m = lv[0];
#pragma unroll
        for (int j = 1; j < 5; ++j) m = fmaxf(m, lv[j]);
#pragma unroll
        for (int off = 16; off >= 1; off >>= 1)
            m = fmaxf(m, __shfl_down(m, off, 32));
        m = __shfl(m, 0, 32);
        float z = 0.f;
#pragma unroll
        for (int j = 0; j < 5; ++j) z += __expf(lv[j] - m);
#pragma unroll
        for (int off = 16; off >= 1; off >>= 1)
            z += __shfl_down(z, off, 32);
        if (t == 0) { sc[0] = m; sc[1] = z; }
    } else if (t >= 64 && t < 96) {
        const int u = t - 64;
        float s = 0.f;
#pragma unroll
        for (int j = 0; j < 5; ++j) s += fch_w[u + 32 * j];
#pragma unroll
        for (int off = 16; off >= 1; off >>= 1)
            s += __shfl_down(s, off, 32);
        if (u == 0) sc[2] = s;
    }
    __syncthreads();

    // ---- row partials: rp = sum_r exp(l[h]-m) * x4  (x4 still in registers) ----
    const float m = sc[0];
    const float Z = sc[1];
    float4 rp = make_float4(0.f, 0.f, 0.f, 0.f);
#pragma unroll
    for (int r = 0; r < RPT; ++r) {
        float a = __expf(larr[v * RPT + r] - m);  // LDS broadcast read
        rp.x += a * xr[r].x; rp.y += a * xr[r].y;
        rp.z += a * xr[r].z; rp.w += a * xr[r].w;
    }
    __syncthreads();  // everyone done reading pbuf/larr-as-logits
    pbuf[v * WW + 4 * q + 0] = rp.x;
    pbuf[v * WW + 4 * q + 1] = rp.y;
    pbuf[v * WW + 4 * q + 2] = rp.z;
    pbuf[v * WW + 4 * q + 3] = rp.w;
    __syncthreads();

    // ---- row[w] = (sum_v rp(v,w)) / Z   (reuse larr as row[]) ----
    if (t < WW) {
        float rs = 0.f;
#pragma unroll
        for (int vv = 0; vv < 8; ++vv) rs += pbuf[vv * WW + t];
        larr[t] = rs / Z;
    }
    __syncthreads();

    // ---- wave0: beta softmax + s = sum beta*row ----
    if (t < 32) {
        const float S = sc[2];
        float rv[5], bl[5];
#pragma unroll
        for (int j = 0; j < 5; ++j) { rv[j] = larr[t + 32 * j]; bl[j] = rv[j] * S; }
        float mb = bl[0];
#pragma unroll
        for (int j = 1; j < 5; ++j) mb = fmaxf(mb, bl[j]);
#pragma unroll
        for (int off = 16; off >= 1; off >>= 1)
            mb = fmaxf(mb, __shfl_down(mb, off, 32));
        mb = __shfl(mb, 0, 32);
        float zb = 0.f, sd = 0.f;
#pragma unroll
        for (int j = 0; j < 5; ++j) {
            float e = __expf(bl[j] - mb);
            zb += e; sd += e * rv[j];
        }
#pragma unroll
        for (int off = 16; off >= 1; off >>= 1) {
            zb += __shfl_down(zb, off, 32);
            sd += __shfl_down(sd, off, 32);
        }
        if (t == 0) sc[3] = sd / zb;
    }
    __syncthreads();

    // ---- broadcast store (coalesced float4) ----
    const float sv = sc[3];
    const float4 o = make_float4(sv, sv, sv, sv);
#pragma unroll
    for (int r = 0; r < RPT; ++r)
        *(float4*)(op + (size_t)(v * RPT + r) * WW + 4 * q) = o;
}

extern "C" void kernel_launch(void* const* d_in, const int* in_sizes, int n_in,
                              void* d_out, int out_size, void* d_ws, size_t ws_size,
                              hipStream_t stream) {
    const float* x     = (const float*)d_in[0];
    const float* fcw_w = (const float*)d_in[1];
    // d_in[2] = fcw_b: softmax-shift-invariant, unused
    const float* fch_w = (const float*)d_in[3];
    // d_in[4] = fch_b: softmax-shift-invariant, unused
    float* out = (float*)d_out;

    const int nplanes = 8 * 256;  // B*C
    sa1_kernel<<<nplanes, BLOCK, 0, stream>>>(x, fcw_w, fch_w, out);
}